// Round 15
// baseline (524.856 us; speedup 1.0000x reference)
//
#include <hip/hip_runtime.h>

// Problem constants
#define BB 8
#define NN 4096
#define CC 128
#define RR 16
#define EE 65536
#define NNODES 32768
#define NEDGES 524288
#define BCAP   60                // per-dst bucket capacity (Poisson16: P(ovf)~1e-11)
#define LDK    136               // bf16 LDS row stride for K=128 tiles (272B, 16B-aligned)
#define LDAW   132               // fp32 accumulator row stride (floats)
#define ELMAX  3072              // per-block edge list cap (mean 2048, +22 sigma)

typedef unsigned short ushort_t;
typedef short bf16x8 __attribute__((ext_vector_type(8)));
typedef float f32x4 __attribute__((ext_vector_type(4)));

__device__ __forceinline__ unsigned short f2b(float f) {
    unsigned u = __builtin_bit_cast(unsigned, f);
    unsigned r = (u + 0x7fffu + ((u >> 16) & 1u)) >> 16;   // RNE
    return (unsigned short)r;
}
__device__ __forceinline__ float b2f(unsigned short s) {
    return __builtin_bit_cast(float, (unsigned)s << 16);
}
__device__ __forceinline__ float ldf(const void* p, int j, int isbf) {
    return isbf ? b2f(((const ushort_t*)p)[j]) : ((const float*)p)[j];
}
__device__ __forceinline__ int ldi(const int* p, int j, int is64) {
    return p[j << is64];
}

__device__ __forceinline__ int probe_isbf(const ushort_t* xf) {
    int t = threadIdx.x & 63;
    int bad = 0;
    for (int j = t; j < 512; j += 64) {
        unsigned e = (xf[j] >> 7) & 0xffu;
        if (e >= 160u) bad = 1;
    }
    return __ballot(bad) == 0ull;
}

// ---------- pe_k: edge bucketing (FIRST) + casts + flags ----------
// [0,2048): edge append | [2048,4096): cast x->Xb | [4096,5184): weights->WT | 5184: flags
__global__ __launch_bounds__(256) void pe_k(const void* __restrict__ x,
                                            const void* __restrict__ relw,
                                            const void* __restrict__ rootw,
                                            const int* __restrict__ ei,
                                            const int* __restrict__ et,
                                            ushort_t* __restrict__ Xb,
                                            ushort_t* __restrict__ WT,
                                            int* __restrict__ dcnt,
                                            int* __restrict__ bucket,
                                            int* __restrict__ flags) {
    int bx = blockIdx.x, t = threadIdx.x;
    if (bx < 2048) {                       // ---- edge path ----
        __shared__ int sw64i, sw64t;
        if (t < 64) {
            int a = (t < 16) ? ei[2 * t + 1] : 0;
            int b = (t < 16) ? et[2 * t + 1] : 0;
            unsigned long long ma = __ballot(a != 0);
            unsigned long long mb = __ballot(b != 0);
            if (t == 0) { sw64i = (ma == 0ull); sw64t = (mb == 0ull); }
        }
        __syncthreads();
        int w64i = sw64i, w64t = sw64t;
        int tid = bx * 256 + t;            // < NEDGES
        int b = tid >> 16, e = tid & 65535;
        int src = ldi(ei, (b * 2) * EE + e, w64i);
        int dst = ldi(ei, (b * 2 + 1) * EE + e, w64i);
        int r = ldi(et, tid, w64t);
        int gd = (b << 12) + dst;
        int pos = atomicAdd(&dcnt[gd], 1);
        if (pos < BCAP)
            bucket[gd * BCAP + pos] = (((b << 12) + src) << 4) | r;
    } else if (bx < 4096) {                // ---- cast_x ----
        int isbf = probe_isbf((const ushort_t*)x);
        int tid = (bx - 2048) * 256 + t;   // < 524288
        if (isbf) {
            ((uint4*)Xb)[tid] = ((const uint4*)x)[tid];
        } else {
            const float4* xf = (const float4*)x;
            float4 a = xf[2 * tid], b = xf[2 * tid + 1];
            ushort4 o0, o1;
            o0.x = f2b(a.x); o0.y = f2b(a.y); o0.z = f2b(a.z); o0.w = f2b(a.w);
            o1.x = f2b(b.x); o1.y = f2b(b.y); o1.z = f2b(b.z); o1.w = f2b(b.w);
            ((ushort4*)Xb)[2 * tid] = o0; ((ushort4*)Xb)[2 * tid + 1] = o1;
        }
    } else if (bx < 5184) {                // ---- cast_w: WT[nglob][k] = Wall[k][nglob] ----
        int isbf = probe_isbf((const ushort_t*)x);
        int tid = (bx - 4096) * 256 + t;   // < 278528
        int nglob = tid >> 7, k = tid & 127;
        int jb = nglob >> 7, n = nglob & 127;
        float v = (jb == 0) ? ldf(rootw, k * 128 + n, isbf)
                            : ldf(relw, ((jb - 1) << 14) + k * 128 + n, isbf);
        WT[tid] = f2b(v);
    } else {
        if (t < 64) {
            int isbf = probe_isbf((const ushort_t*)x);
            if (t == 0) flags[0] = isbf;
        }
    }
}

// ---------- rgcn_fused_k: counting-sort + parallel mean-gather + MFMA + score ----------
// One block per 128 nodes. No Y materialization. LDS ~158 KB, 1 block/CU.
// R14 bug fixed: K=128 tiles need row stride >= 128 shorts (LDK=136), not 80.
__global__ __launch_bounds__(256, 1) void rgcn_fused_k(const ushort_t* __restrict__ Xb,
                                                       const ushort_t* __restrict__ WT,
                                                       const int* __restrict__ dcnt,
                                                       const int* __restrict__ bucket,
                                                       const void* __restrict__ bias,
                                                       const void* __restrict__ linw,
                                                       const void* __restrict__ linb,
                                                       void* __restrict__ out,
                                                       const int* __restrict__ flags) {
    __shared__ float    Aacc[128 * LDAW];      // 67,584 B fp32 mean accumulator
    __shared__ ushort_t Abf[128 * LDK];        // 34,816 B bf16 A tile
    __shared__ ushort_t Bs[128 * LDK];         // 34,816 B bf16 B tile
    __shared__ int      elist[ELMAX];          // 12,288 B rel-sorted edges
    __shared__ int      cnt16[128 * 16];       //  8,192 B per-(node,rel) counts
    __shared__ int      rcnt[16], roff[17], rcur[16];
    __shared__ float    scorebuf[128];

    int t = threadIdx.x;
    int m0 = blockIdx.x * 128;
    int isbf = flags[0];

    if (t < 16) { rcnt[t] = 0; rcur[t] = 0; }
    if (t < 128) scorebuf[t] = 0.f;
    for (int idx = t; idx < 128 * 16; idx += 256) cnt16[idx] = 0;
    __syncthreads();

    // Pass A: count per rel (block) and per (node,rel)
    int node = t >> 1, half = t & 1;
    int nc = dcnt[m0 + node]; if (nc > BCAP) nc = BCAP;
    const int* bk = bucket + (size_t)(m0 + node) * BCAP;
    for (int j = half; j < nc; j += 2) {
        int r = bk[j] & 15;
        atomicAdd(&rcnt[r], 1);
        atomicAdd(&cnt16[node * 16 + r], 1);
    }
    __syncthreads();
    if (t == 0) {
        int s = 0;
        for (int r = 0; r < 16; ++r) { roff[r] = s; s += rcnt[r]; }
        roff[16] = s;
    }
    __syncthreads();
    // Pass B: place edges into rel segments: entry = (node_local<<15)|src_global
    for (int j = half; j < nc; j += 2) {
        int v = bk[j];
        int r = v & 15;
        int pos = roff[r] + atomicAdd(&rcur[r], 1);
        if (pos < ELMAX) elist[pos] = (node << 15) | (v >> 4);
    }
    __syncthreads();

    int wave = t >> 6, lane = t & 63, lrow = lane & 15, lq = lane >> 4;
    int wm = (wave >> 1) * 64, wn = (wave & 1) * 64;
    int g = t >> 4, l16 = t & 15;          // 16 gather groups x 16 lanes
    f32x4 acc[4][4] = {};

    for (int jb = 0; jb < 17; ++jb) {
        // stage B = W_jb^T (128x128): 2048 uint4, 8/thread
        #pragma unroll
        for (int i = 0; i < 8; ++i) {
            int c = t + i * 256;
            int row = c >> 4, c16 = c & 15;
            uint4 vb = *(const uint4*)(WT + (((size_t)(jb * 128 + row)) << 7) + c16 * 8);
            *(uint4*)(&Bs[row * LDK + c16 * 8]) = vb;
        }
        if (jb == 0) {                     // root phase: A = Xb rows
            #pragma unroll
            for (int i = 0; i < 8; ++i) {
                int c = t + i * 256;
                int row = c >> 4, c16 = c & 15;
                uint4 va = *(const uint4*)(Xb + (((size_t)(m0 + row)) << 7) + c16 * 8);
                *(uint4*)(&Abf[row * LDK + c16 * 8]) = va;
            }
            __syncthreads();
        } else {
            int r = jb - 1;
            for (int idx = t; idx < 128 * LDAW / 4; idx += 256)
                *(float4*)(&Aacc[idx * 4]) = make_float4(0.f, 0.f, 0.f, 0.f);
            __syncthreads();
            // parallel gather: group takes edges e0+g, e0+g+16, ...; 4 in flight
            int e0 = roff[r], e1 = roff[r + 1]; if (e1 > ELMAX) e1 = ELMAX;
            int e = e0 + g;
            for (; e + 48 < e1; e += 64) {
                int v0 = elist[e], v1 = elist[e + 16], v2 = elist[e + 32], v3 = elist[e + 48];
                uint4 u0 = *(const uint4*)(Xb + (((size_t)(v0 & 32767)) << 7) + l16 * 8);
                uint4 u1 = *(const uint4*)(Xb + (((size_t)(v1 & 32767)) << 7) + l16 * 8);
                uint4 u2 = *(const uint4*)(Xb + (((size_t)(v2 & 32767)) << 7) + l16 * 8);
                uint4 u3 = *(const uint4*)(Xb + (((size_t)(v3 & 32767)) << 7) + l16 * 8);
                float* a0 = &Aacc[(v0 >> 15) * LDAW + l16 * 8];
                float* a1 = &Aacc[(v1 >> 15) * LDAW + l16 * 8];
                float* a2 = &Aacc[(v2 >> 15) * LDAW + l16 * 8];
                float* a3 = &Aacc[(v3 >> 15) * LDAW + l16 * 8];
                #pragma unroll
                for (int q = 0; q < 4; ++q) {
                    unsigned w0 = (&u0.x)[q], w1 = (&u1.x)[q], w2 = (&u2.x)[q], w3 = (&u3.x)[q];
                    atomicAdd(&a0[2 * q],     b2f((ushort_t)(w0 & 0xffff)));
                    atomicAdd(&a0[2 * q + 1], b2f((ushort_t)(w0 >> 16)));
                    atomicAdd(&a1[2 * q],     b2f((ushort_t)(w1 & 0xffff)));
                    atomicAdd(&a1[2 * q + 1], b2f((ushort_t)(w1 >> 16)));
                    atomicAdd(&a2[2 * q],     b2f((ushort_t)(w2 & 0xffff)));
                    atomicAdd(&a2[2 * q + 1], b2f((ushort_t)(w2 >> 16)));
                    atomicAdd(&a3[2 * q],     b2f((ushort_t)(w3 & 0xffff)));
                    atomicAdd(&a3[2 * q + 1], b2f((ushort_t)(w3 >> 16)));
                }
            }
            for (; e < e1; e += 16) {
                int v0 = elist[e];
                uint4 u0 = *(const uint4*)(Xb + (((size_t)(v0 & 32767)) << 7) + l16 * 8);
                float* a0 = &Aacc[(v0 >> 15) * LDAW + l16 * 8];
                #pragma unroll
                for (int q = 0; q < 4; ++q) {
                    unsigned w0 = (&u0.x)[q];
                    atomicAdd(&a0[2 * q],     b2f((ushort_t)(w0 & 0xffff)));
                    atomicAdd(&a0[2 * q + 1], b2f((ushort_t)(w0 >> 16)));
                }
            }
            __syncthreads();
            // convert: mean = Aacc * (1/cnt) -> bf16 Abf (thread: 64 cols of 1 node)
            {
                int cv = cnt16[node * 16 + r];
                float inv = (cv > 0) ? 1.0f / (float)cv : 0.f;
                const float* ap = &Aacc[node * LDAW + half * 64];
                ushort_t* bp = &Abf[node * LDK + half * 64];
                #pragma unroll
                for (int q = 0; q < 8; ++q) {
                    uint4 o;
                    o.x = ((unsigned)f2b(ap[q * 8 + 1] * inv) << 16) | f2b(ap[q * 8 + 0] * inv);
                    o.y = ((unsigned)f2b(ap[q * 8 + 3] * inv) << 16) | f2b(ap[q * 8 + 2] * inv);
                    o.z = ((unsigned)f2b(ap[q * 8 + 5] * inv) << 16) | f2b(ap[q * 8 + 4] * inv);
                    o.w = ((unsigned)f2b(ap[q * 8 + 7] * inv) << 16) | f2b(ap[q * 8 + 6] * inv);
                    *(uint4*)(&bp[q * 8]) = o;
                }
            }
            __syncthreads();
        }
        // MFMA: acc += A_jb @ W_jb (K=128; acc persists across phases)
        #pragma unroll
        for (int ks = 0; ks < 4; ++ks) {
            int k0 = ks * 32 + lq * 8;
            bf16x8 a[4], b[4];
            #pragma unroll
            for (int mi = 0; mi < 4; ++mi) a[mi] = *(const bf16x8*)(&Abf[(wm + mi * 16 + lrow) * LDK + k0]);
            #pragma unroll
            for (int ni = 0; ni < 4; ++ni) b[ni] = *(const bf16x8*)(&Bs[(wn + ni * 16 + lrow) * LDK + k0]);
            #pragma unroll
            for (int mi = 0; mi < 4; ++mi)
                #pragma unroll
                for (int ni = 0; ni < 4; ++ni)
                    acc[mi][ni] = __builtin_amdgcn_mfma_f32_16x16x32_bf16(a[mi], b[ni], acc[mi][ni], 0, 0, 0);
        }
        __syncthreads();
    }

    // epilogue (R11-verified): relu(acc+bias)*linw, reduce cols -> score per node
    float bcol[4], lcol[4];
    #pragma unroll
    for (int ni = 0; ni < 4; ++ni) {
        int col = wn + ni * 16 + lrow;
        bcol[ni] = ldf(bias, col, isbf);
        lcol[ni] = ldf(linw, col, isbf);
    }
    #pragma unroll
    for (int mi = 0; mi < 4; ++mi)
        #pragma unroll
        for (int rg = 0; rg < 4; ++rg) {
            float s = 0.f;
            #pragma unroll
            for (int ni = 0; ni < 4; ++ni)
                s += fmaxf(acc[mi][ni][rg] + bcol[ni], 0.f) * lcol[ni];
            s += __shfl_down(s, 8, 16);
            s += __shfl_down(s, 4, 16);
            s += __shfl_down(s, 2, 16);
            s += __shfl_down(s, 1, 16);
            if (lrow == 0) atomicAdd(&scorebuf[wm + mi * 16 + lq * 4 + rg], s);
        }
    __syncthreads();
    if (t < 128) {
        float res = scorebuf[t] + ldf(linb, 0, isbf);
        if (isbf) ((ushort_t*)out)[m0 + t] = f2b(res);
        else      ((float*)out)[m0 + t] = res;
    }
}

extern "C" void kernel_launch(void* const* d_in, const int* in_sizes, int n_in,
                              void* d_out, int out_size, void* d_ws, size_t ws_size,
                              hipStream_t stream) {
    const void* x     = d_in[0];
    const int*  ei    = (const int*)d_in[1];
    const int*  et    = (const int*)d_in[2];
    const void* relw  = d_in[3];
    const void* rootw = d_in[4];
    const void* bias  = d_in[5];
    const void* linw  = d_in[6];
    const void* linb  = d_in[7];

    const size_t WS_NEED = 16941568;
    if (ws_size < WS_NEED) return;

    char* ws = (char*)d_ws;
    ushort_t* Xb     = (ushort_t*)(ws);                       // 8,388,608
    ushort_t* WT     = (ushort_t*)(ws + 8388608);             // 557,056
    int*      dcnt   = (int*)(ws + 8945664);                  // 131,072
    int*      bucket = (int*)(ws + 9076736);                  // 7,864,320
    int*      flags  = (int*)(ws + 16941056);                 // 256

    hipMemsetAsync(dcnt, 0, 131072, stream);
    pe_k<<<5185, 256, 0, stream>>>(x, relw, rootw, ei, et, Xb, WT, dcnt, bucket, flags);
    rgcn_fused_k<<<256, 256, 0, stream>>>(Xb, WT, dcnt, bucket, bias, linw, linb, d_out, flags);
}

// Round 16
// 204.569 us; speedup vs baseline: 2.5657x; 2.5657x over previous
//
#include <hip/hip_runtime.h>

// Problem constants
#define BB 8
#define NN 4096
#define CC 128
#define RR 16
#define EE 65536
#define NNODES 32768
#define NEDGES 524288
#define KTOT   2176              // 17*128 columns of Y: [root | rel0..rel15]
#define LDP    80                // LDS row stride (shorts): 160B, 16B-aligned/row
#define CSP    136               // epilogue LDS stride: 272B, 16B-aligned/row
#define BCAP   60                // per-dst bucket capacity (Poisson16: P(ovf)~1e-11)
#define GEMMB  4352              // 256 m-tiles * 17 n-tiles
#define EDGEB  2048              // edge-family blocks (dispatched FIRST)

typedef unsigned short ushort_t;
typedef short bf16x8 __attribute__((ext_vector_type(8)));
typedef float f32x4 __attribute__((ext_vector_type(4)));

__device__ __forceinline__ unsigned short f2b(float f) {
    unsigned u = __builtin_bit_cast(unsigned, f);
    unsigned r = (u + 0x7fffu + ((u >> 16) & 1u)) >> 16;   // RNE
    return (unsigned short)r;
}
__device__ __forceinline__ float b2f(unsigned short s) {
    return __builtin_bit_cast(float, (unsigned)s << 16);
}
__device__ __forceinline__ float ldf(const void* p, int j, int isbf) {
    return isbf ? b2f(((const ushort_t*)p)[j]) : ((const float*)p)[j];
}
__device__ __forceinline__ int ldi(const int* p, int j, int is64) {
    return p[j << is64];
}

// wave-parallel float-dtype probe: fp32 mantissa noise shows huge bf16 "exponent"
__device__ __forceinline__ int probe_isbf(const ushort_t* xf) {
    int t = threadIdx.x & 63;
    int bad = 0;
    for (int j = t; j < 512; j += 64) {
        unsigned e = (xf[j] >> 7) & 0xffu;
        if (e >= 160u) bad = 1;
    }
    return __ballot(bad) == 0ull;
}

// ---------- wprep_k: WT cast + dcnt zeroing + flags (no Xb anymore) ----------
// [0,1088): weights->WT | [1088,1120): zero dcnt | 1120: flags
__global__ __launch_bounds__(256) void wprep_k(const void* __restrict__ x,
                                               const void* __restrict__ relw,
                                               const void* __restrict__ rootw,
                                               const int* __restrict__ ei,
                                               const int* __restrict__ et,
                                               ushort_t* __restrict__ WT,
                                               int* __restrict__ dcnt,
                                               int* __restrict__ flags) {
    int bx = blockIdx.x, t = threadIdx.x;
    if (bx < 1088) {                       // cast_w: WT[nglob][k] = Wall[k][nglob]
        int isbf = probe_isbf((const ushort_t*)x);
        int tid = bx * 256 + t;            // < 278528
        int nglob = tid >> 7, k = tid & 127;
        int jb = nglob >> 7, n = nglob & 127;
        float v = (jb == 0) ? ldf(rootw, k * 128 + n, isbf)
                            : ldf(relw, ((jb - 1) << 14) + k * 128 + n, isbf);
        WT[tid] = f2b(v);
    } else if (bx < 1120) {                // zero dcnt (8192 uint4)
        int tid = (bx - 1088) * 256 + t;
        ((uint4*)dcnt)[tid] = make_uint4(0, 0, 0, 0);
    } else {                               // flags
        if (t < 64) {
            int isbf = probe_isbf((const ushort_t*)x);
            int a = (t < 16) ? ei[2 * t + 1] : 0;
            int b = (t < 16) ? et[2 * t + 1] : 0;
            unsigned long long ma = __ballot(a != 0);
            unsigned long long mb = __ballot(b != 0);
            if (t == 0) {
                flags[0] = isbf;
                flags[1] = (ma == 0ull);
                flags[2] = (mb == 0ull);
            }
        }
    }
}

// ---------- ge_k: fused edge bucketing (FIRST) + MFMA GEMM (A staged from x) ----------
// blocks [0,EDGEB): edge append; [EDGEB, EDGEB+GEMMB): Y = x @ Wall with
// in-register fp32->bf16 convert during A-staging (x is L3-resident; no Xb).
__global__ __launch_bounds__(256) void ge_k(const void* __restrict__ x,
                                            const ushort_t* __restrict__ WT,
                                            ushort_t* __restrict__ Y,
                                            const int* __restrict__ ei,
                                            const int* __restrict__ et,
                                            int* __restrict__ dcnt,
                                            int* __restrict__ bucket,
                                            const int* __restrict__ flags) {
    __shared__ ushort_t smem[2 * 128 * LDP];   // As | Bs; reused as Cs in epilogue
    int bx = blockIdx.x, t = threadIdx.x;
    if (bx < EDGEB) {                      // ---- edge path: one edge per thread ----
        int w64i = flags[1], w64t = flags[2];
        int tid = bx * 256 + t;            // < NEDGES
        int b = tid >> 16, e = tid & 65535;
        int src = ldi(ei, (b * 2) * EE + e, w64i);
        int dst = ldi(ei, (b * 2 + 1) * EE + e, w64i);
        int r = ldi(et, tid, w64t);
        int gd = (b << 12) + dst;
        int pos = atomicAdd(&dcnt[gd], 1);
        if (pos < BCAP)
            bucket[gd * BCAP + pos] = (((b << 12) + src) << 4) | r;
        return;
    }
    // ---- gemm path ----
    int bxg = bx - EDGEB;
    int isbf = flags[0];
    ushort_t* As = smem;                   // [128][LDP]
    ushort_t* Bs = smem + 128 * LDP;       // [128][LDP]
    int m0 = (bxg & 255) * 128, n0 = (bxg >> 8) * 128;
    int wave = t >> 6, lane = t & 63, lrow = lane & 15, lq = lane >> 4;
    int wm = (wave >> 1) * 64, wn = (wave & 1) * 64;
    f32x4 acc[4][4] = {};

    for (int kt = 0; kt < 2; ++kt) {
        #pragma unroll
        for (int i = 0; i < 4; ++i) {
            int c = t + i * 256;
            int row = c >> 3, c8 = c & 7;
            size_t off = (size_t)(m0 + row) * 128 + kt * 64 + c8 * 8;
            if (isbf) {
                uint4 va = *(const uint4*)((const ushort_t*)x + off);
                *(uint4*)(&As[row * LDP + c8 * 8]) = va;
            } else {
                const float* xp = (const float*)x + off;
                float4 f0 = *(const float4*)xp;
                float4 f1 = *(const float4*)(xp + 4);
                uint4 o;
                o.x = ((unsigned)f2b(f0.y) << 16) | f2b(f0.x);
                o.y = ((unsigned)f2b(f0.w) << 16) | f2b(f0.z);
                o.z = ((unsigned)f2b(f1.y) << 16) | f2b(f1.x);
                o.w = ((unsigned)f2b(f1.w) << 16) | f2b(f1.z);
                *(uint4*)(&As[row * LDP + c8 * 8]) = o;
            }
            uint4 vb = *(const uint4*)(WT + (size_t)(n0 + row) * 128 + kt * 64 + c8 * 8);
            *(uint4*)(&Bs[row * LDP + c8 * 8]) = vb;
        }
        __syncthreads();
        #pragma unroll
        for (int ks = 0; ks < 2; ++ks) {
            int k0 = ks * 32 + lq * 8;
            bf16x8 a[4], b[4];
            #pragma unroll
            for (int mi = 0; mi < 4; ++mi) a[mi] = *(const bf16x8*)(&As[(wm + mi * 16 + lrow) * LDP + k0]);
            #pragma unroll
            for (int ni = 0; ni < 4; ++ni) b[ni] = *(const bf16x8*)(&Bs[(wn + ni * 16 + lrow) * LDP + k0]);
            #pragma unroll
            for (int mi = 0; mi < 4; ++mi)
                #pragma unroll
                for (int ni = 0; ni < 4; ++ni)
                    acc[mi][ni] = __builtin_amdgcn_mfma_f32_16x16x32_bf16(a[mi], b[ni], acc[mi][ni], 0, 0, 0);
        }
        __syncthreads();
    }
    // Epilogue via LDS -> coalesced uint4 stores (R12/R13-verified)
    ushort_t* Cs = smem;                   // [128][CSP]
    #pragma unroll
    for (int mi = 0; mi < 4; ++mi)
        #pragma unroll
        for (int rg = 0; rg < 4; ++rg) {
            int row = wm + mi * 16 + lq * 4 + rg;
            #pragma unroll
            for (int ni = 0; ni < 4; ++ni)
                Cs[row * CSP + wn + ni * 16 + lrow] = f2b(acc[mi][ni][rg]);
        }
    __syncthreads();
    #pragma unroll
    for (int i = 0; i < 8; ++i) {
        int c = t + i * 256;
        int row = c >> 4, c16 = c & 15;
        uint4 v = *(const uint4*)(&Cs[row * CSP + c16 * 8]);
        *(uint4*)(Y + (size_t)(m0 + row) * KTOT + n0 + c16 * 8) = v;
    }
}

// ---------- agg: group-gather (16 lanes x uint4 = full 256B row per group) ----------
// (R13-verified) 128 threads = 8 groups; partials reduce via part[128][9] LDS.
__global__ __launch_bounds__(128) void agg_score_k(const ushort_t* __restrict__ Y,
                                                   const int* __restrict__ dcnt,
                                                   const int* __restrict__ bucket,
                                                   const void* __restrict__ bias,
                                                   const void* __restrict__ linw,
                                                   const void* __restrict__ linb,
                                                   void* __restrict__ out,
                                                   const int* __restrict__ flags) {
    int i = blockIdx.x, t = threadIdx.x;
    int isbf = flags[0];
    __shared__ int scnt[RR];
    __shared__ float inv[RR];
    __shared__ int bke[64];
    __shared__ float part[128][9];
    int nc = dcnt[i]; if (nc > BCAP) nc = BCAP;
    const int* bk = bucket + i * BCAP;
    if (t < RR) scnt[t] = 0;
    __syncthreads();
    if (t < nc) { int v = bk[t]; bke[t] = v; atomicAdd(&scnt[v & 15], 1); }
    __syncthreads();
    if (t < RR) inv[t] = (scnt[t] > 0) ? 1.0f / (float)scnt[t] : 0.0f;
    __syncthreads();

    int g = t >> 4, l16 = t & 15;          // group, lane-in-group
    float a8[8] = {};
    for (int base = 0; base < nc; base += 8) {
        int e = base + g;
        if (e < nc) {
            int v = bke[e];
            const ushort_t* yr = Y + (size_t)(v >> 4) * KTOT + CC + ((v & 15) << 7) + l16 * 8;
            uint4 u = *(const uint4*)yr;
            float w = inv[v & 15];
            a8[0] += w * __builtin_bit_cast(float, u.x << 16);
            a8[1] += w * __builtin_bit_cast(float, u.x & 0xffff0000u);
            a8[2] += w * __builtin_bit_cast(float, u.y << 16);
            a8[3] += w * __builtin_bit_cast(float, u.y & 0xffff0000u);
            a8[4] += w * __builtin_bit_cast(float, u.z << 16);
            a8[5] += w * __builtin_bit_cast(float, u.z & 0xffff0000u);
            a8[6] += w * __builtin_bit_cast(float, u.w << 16);
            a8[7] += w * __builtin_bit_cast(float, u.w & 0xffff0000u);
        }
    }
    #pragma unroll
    for (int j = 0; j < 8; ++j) part[l16 * 8 + j][g] = a8[j];
    __syncthreads();

    float acc = b2f(Y[(size_t)i * KTOT + t]) + ldf(bias, t, isbf);
    #pragma unroll
    for (int gg = 0; gg < 8; ++gg) acc += part[t][gg];
    float val = fmaxf(acc, 0.f) * ldf(linw, t, isbf);
    for (int o = 32; o > 0; o >>= 1) val += __shfl_down(val, o, 64);
    __shared__ float red[2];
    if ((t & 63) == 0) red[t >> 6] = val;
    __syncthreads();
    if (t == 0) {
        float res = red[0] + red[1] + ldf(linb, 0, isbf);
        if (isbf) ((ushort_t*)out)[i] = f2b(res);
        else      ((float*)out)[i] = res;
    }
}

extern "C" void kernel_launch(void* const* d_in, const int* in_sizes, int n_in,
                              void* d_out, int out_size, void* d_ws, size_t ws_size,
                              hipStream_t stream) {
    const void* x     = d_in[0];
    const int*  ei    = (const int*)d_in[1];
    const int*  et    = (const int*)d_in[2];
    const void* relw  = d_in[3];
    const void* rootw = d_in[4];
    const void* bias  = d_in[5];
    const void* linw  = d_in[6];
    const void* linb  = d_in[7];

    const size_t WS_NEED = 151159040;
    if (ws_size < WS_NEED) return;

    char* ws = (char*)d_ws;
    ushort_t* Y      = (ushort_t*)(ws);                       // 142,606,336
    ushort_t* WT     = (ushort_t*)(ws + 142606336);           // 557,056
    int*      dcnt   = (int*)(ws + 143163392);                // 131,072
    int*      bucket = (int*)(ws + 143294464);                // 7,864,320
    int*      flags  = (int*)(ws + 151158784);                // 256

    wprep_k<<<1121, 256, 0, stream>>>(x, relw, rootw, ei, et, WT, dcnt, flags);
    ge_k<<<EDGEB + GEMMB, 256, 0, stream>>>(x, WT, Y, ei, et, dcnt, bucket, flags);
    agg_score_k<<<NNODES, 128, 0, stream>>>(Y, dcnt, bucket, bias, linw, linb, d_out, flags);
}

// Round 17
// 166.882 us; speedup vs baseline: 3.1451x; 1.2258x over previous
//
#include <hip/hip_runtime.h>

// Problem constants
#define BB 8
#define NN 4096
#define CC 128
#define RR 16
#define EE 65536
#define NNODES 32768
#define NEDGES 524288
#define KTOT   2176              // 17*128 columns of Y: [root | rel0..rel15]
#define LDP    80                // LDS row stride (shorts): 160B, 16B-aligned/row
#define CSP    136               // epilogue LDS stride: 272B, 16B-aligned/row
#define BCAP   60                // per-dst bucket capacity (Poisson16: P(ovf)~1e-11)
#define GEMMB  4352              // 256 m-tiles * 17 n-tiles
#define EDGEB  2048              // edge-family blocks (dispatched FIRST)

typedef unsigned short ushort_t;
typedef short bf16x8 __attribute__((ext_vector_type(8)));
typedef float f32x4 __attribute__((ext_vector_type(4)));

__device__ __forceinline__ unsigned short f2b(float f) {
    unsigned u = __builtin_bit_cast(unsigned, f);
    unsigned r = (u + 0x7fffu + ((u >> 16) & 1u)) >> 16;   // RNE
    return (unsigned short)r;
}
__device__ __forceinline__ float b2f(unsigned short s) {
    return __builtin_bit_cast(float, (unsigned)s << 16);
}
__device__ __forceinline__ float ldf(const void* p, int j, int isbf) {
    return isbf ? b2f(((const ushort_t*)p)[j]) : ((const float*)p)[j];
}
__device__ __forceinline__ int ldi(const int* p, int j, int is64) {
    return p[j << is64];
}

// wave-parallel float-dtype probe: fp32 mantissa noise shows huge bf16 "exponent"
__device__ __forceinline__ int probe_isbf(const ushort_t* xf) {
    int t = threadIdx.x & 63;
    int bad = 0;
    for (int j = t; j < 512; j += 64) {
        unsigned e = (xf[j] >> 7) & 0xffu;
        if (e >= 160u) bad = 1;
    }
    return __ballot(bad) == 0ull;
}

// ---------- prep_k: casts + dcnt zeroing + flag publication ----------
// [0,2048): cast x->Xb | [2048,3136): weights->WT | [3136,3168): zero dcnt | 3168: flags
__global__ __launch_bounds__(256) void prep_k(const void* __restrict__ x,
                                              const void* __restrict__ relw,
                                              const void* __restrict__ rootw,
                                              const int* __restrict__ ei,
                                              const int* __restrict__ et,
                                              ushort_t* __restrict__ Xb,
                                              ushort_t* __restrict__ WT,
                                              int* __restrict__ dcnt,
                                              int* __restrict__ flags) {
    int bx = blockIdx.x, t = threadIdx.x;
    if (bx < 2048) {                       // cast_x: uint4 group per thread
        int isbf = probe_isbf((const ushort_t*)x);
        int tid = bx * 256 + t;            // < 524288
        if (isbf) {
            ((uint4*)Xb)[tid] = ((const uint4*)x)[tid];
        } else {
            const float4* xf = (const float4*)x;
            float4 a = xf[2 * tid], b = xf[2 * tid + 1];
            ushort4 o0, o1;
            o0.x = f2b(a.x); o0.y = f2b(a.y); o0.z = f2b(a.z); o0.w = f2b(a.w);
            o1.x = f2b(b.x); o1.y = f2b(b.y); o1.z = f2b(b.z); o1.w = f2b(b.w);
            ((ushort4*)Xb)[2 * tid] = o0; ((ushort4*)Xb)[2 * tid + 1] = o1;
        }
    } else if (bx < 3136) {                // cast_w: WT[nglob][k] = Wall[k][nglob]
        int isbf = probe_isbf((const ushort_t*)x);
        int tid = (bx - 2048) * 256 + t;   // < 278528
        int nglob = tid >> 7, k = tid & 127;
        int jb = nglob >> 7, n = nglob & 127;
        float v = (jb == 0) ? ldf(rootw, k * 128 + n, isbf)
                            : ldf(relw, ((jb - 1) << 14) + k * 128 + n, isbf);
        WT[tid] = f2b(v);
    } else if (bx < 3168) {                // zero dcnt (8192 uint4)
        int tid = (bx - 3136) * 256 + t;
        ((uint4*)dcnt)[tid] = make_uint4(0, 0, 0, 0);
    } else {                               // flags
        if (t < 64) {
            int isbf = probe_isbf((const ushort_t*)x);
            int a = (t < 16) ? ei[2 * t + 1] : 0;
            int b = (t < 16) ? et[2 * t + 1] : 0;
            unsigned long long ma = __ballot(a != 0);
            unsigned long long mb = __ballot(b != 0);
            if (t == 0) {
                flags[0] = isbf;
                flags[1] = (ma == 0ull);
                flags[2] = (mb == 0ull);
            }
        }
    }
}

// ---------- ge_k: fused edge bucketing (FIRST) + MFMA GEMM ----------
// blocks [0,EDGEB): edge append — dispatched first so atomic latency spans the
// whole kernel instead of forming a tail; [EDGEB, EDGEB+GEMMB): Y = Xb @ Wall.
__global__ __launch_bounds__(256) void ge_k(const ushort_t* __restrict__ Xb,
                                            const ushort_t* __restrict__ WT,
                                            ushort_t* __restrict__ Y,
                                            const int* __restrict__ ei,
                                            const int* __restrict__ et,
                                            int* __restrict__ dcnt,
                                            int* __restrict__ bucket,
                                            const int* __restrict__ flags) {
    __shared__ ushort_t smem[2 * 128 * LDP];   // As | Bs; reused as Cs in epilogue
    int bx = blockIdx.x, t = threadIdx.x;
    if (bx < EDGEB) {                      // ---- edge path: one edge per thread ----
        int w64i = flags[1], w64t = flags[2];
        int tid = bx * 256 + t;            // < NEDGES
        int b = tid >> 16, e = tid & 65535;
        int src = ldi(ei, (b * 2) * EE + e, w64i);
        int dst = ldi(ei, (b * 2 + 1) * EE + e, w64i);
        int r = ldi(et, tid, w64t);
        int gd = (b << 12) + dst;
        int pos = atomicAdd(&dcnt[gd], 1);
        if (pos < BCAP)
            bucket[gd * BCAP + pos] = (((b << 12) + src) << 4) | r;
        return;
    }
    // ---- gemm path ----
    int bxg = bx - EDGEB;
    ushort_t* As = smem;                   // [128][LDP]
    ushort_t* Bs = smem + 128 * LDP;       // [128][LDP]
    int m0 = (bxg & 255) * 128, n0 = (bxg >> 8) * 128;
    int wave = t >> 6, lane = t & 63, lrow = lane & 15, lq = lane >> 4;
    int wm = (wave >> 1) * 64, wn = (wave & 1) * 64;
    f32x4 acc[4][4] = {};

    for (int kt = 0; kt < 2; ++kt) {
        #pragma unroll
        for (int i = 0; i < 4; ++i) {
            int c = t + i * 256;
            int row = c >> 3, c8 = c & 7;
            uint4 va = *(const uint4*)(Xb + (size_t)(m0 + row) * 128 + kt * 64 + c8 * 8);
            *(uint4*)(&As[row * LDP + c8 * 8]) = va;
            uint4 vb = *(const uint4*)(WT + (size_t)(n0 + row) * 128 + kt * 64 + c8 * 8);
            *(uint4*)(&Bs[row * LDP + c8 * 8]) = vb;
        }
        __syncthreads();
        #pragma unroll
        for (int ks = 0; ks < 2; ++ks) {
            int k0 = ks * 32 + lq * 8;
            bf16x8 a[4], b[4];
            #pragma unroll
            for (int mi = 0; mi < 4; ++mi) a[mi] = *(const bf16x8*)(&As[(wm + mi * 16 + lrow) * LDP + k0]);
            #pragma unroll
            for (int ni = 0; ni < 4; ++ni) b[ni] = *(const bf16x8*)(&Bs[(wn + ni * 16 + lrow) * LDP + k0]);
            #pragma unroll
            for (int mi = 0; mi < 4; ++mi)
                #pragma unroll
                for (int ni = 0; ni < 4; ++ni)
                    acc[mi][ni] = __builtin_amdgcn_mfma_f32_16x16x32_bf16(a[mi], b[ni], acc[mi][ni], 0, 0, 0);
        }
        __syncthreads();
    }
    // Epilogue via LDS -> coalesced uint4 stores (R12-verified)
    ushort_t* Cs = smem;                   // [128][CSP]
    #pragma unroll
    for (int mi = 0; mi < 4; ++mi)
        #pragma unroll
        for (int rg = 0; rg < 4; ++rg) {
            int row = wm + mi * 16 + lq * 4 + rg;
            #pragma unroll
            for (int ni = 0; ni < 4; ++ni)
                Cs[row * CSP + wn + ni * 16 + lrow] = f2b(acc[mi][ni][rg]);
        }
    __syncthreads();
    #pragma unroll
    for (int i = 0; i < 8; ++i) {
        int c = t + i * 256;
        int row = c >> 4, c16 = c & 15;
        uint4 v = *(const uint4*)(&Cs[row * CSP + c16 * 8]);
        *(uint4*)(Y + (size_t)(m0 + row) * KTOT + n0 + c16 * 8) = v;
    }
}

// ---------- agg: group-gather (16 lanes x uint4 = full 256B row per group) ----------
// 128 threads = 8 groups; group g gathers edges e = base+g. Per-thread 8-col
// partials reduce via part[128][9] LDS (pad 9 -> max 4-way bank conflict).
__global__ __launch_bounds__(128) void agg_score_k(const ushort_t* __restrict__ Y,
                                                   const int* __restrict__ dcnt,
                                                   const int* __restrict__ bucket,
                                                   const void* __restrict__ bias,
                                                   const void* __restrict__ linw,
                                                   const void* __restrict__ linb,
                                                   void* __restrict__ out,
                                                   const int* __restrict__ flags) {
    int i = blockIdx.x, t = threadIdx.x;
    int isbf = flags[0];
    __shared__ int scnt[RR];
    __shared__ float inv[RR];
    __shared__ int bke[64];
    __shared__ float part[128][9];
    int nc = dcnt[i]; if (nc > BCAP) nc = BCAP;
    const int* bk = bucket + i * BCAP;
    if (t < RR) scnt[t] = 0;
    __syncthreads();
    if (t < nc) { int v = bk[t]; bke[t] = v; atomicAdd(&scnt[v & 15], 1); }
    __syncthreads();
    if (t < RR) inv[t] = (scnt[t] > 0) ? 1.0f / (float)scnt[t] : 0.0f;
    __syncthreads();

    int g = t >> 4, l16 = t & 15;          // group, lane-in-group
    float a8[8] = {};
    for (int base = 0; base < nc; base += 8) {
        int e = base + g;
        if (e < nc) {
            int v = bke[e];
            const ushort_t* yr = Y + (size_t)(v >> 4) * KTOT + CC + ((v & 15) << 7) + l16 * 8;
            uint4 u = *(const uint4*)yr;
            float w = inv[v & 15];
            a8[0] += w * __builtin_bit_cast(float, u.x << 16);
            a8[1] += w * __builtin_bit_cast(float, u.x & 0xffff0000u);
            a8[2] += w * __builtin_bit_cast(float, u.y << 16);
            a8[3] += w * __builtin_bit_cast(float, u.y & 0xffff0000u);
            a8[4] += w * __builtin_bit_cast(float, u.z << 16);
            a8[5] += w * __builtin_bit_cast(float, u.z & 0xffff0000u);
            a8[6] += w * __builtin_bit_cast(float, u.w << 16);
            a8[7] += w * __builtin_bit_cast(float, u.w & 0xffff0000u);
        }
    }
    #pragma unroll
    for (int j = 0; j < 8; ++j) part[l16 * 8 + j][g] = a8[j];
    __syncthreads();

    // col t: sum 8 group partials + root + bias, relu, * linw, reduce
    float acc = b2f(Y[(size_t)i * KTOT + t]) + ldf(bias, t, isbf);
    #pragma unroll
    for (int gg = 0; gg < 8; ++gg) acc += part[t][gg];
    float val = fmaxf(acc, 0.f) * ldf(linw, t, isbf);
    for (int o = 32; o > 0; o >>= 1) val += __shfl_down(val, o, 64);
    __shared__ float red[2];
    if ((t & 63) == 0) red[t >> 6] = val;
    __syncthreads();
    if (t == 0) {
        float res = red[0] + red[1] + ldf(linb, 0, isbf);
        if (isbf) ((ushort_t*)out)[i] = f2b(res);
        else      ((float*)out)[i] = res;
    }
}

extern "C" void kernel_launch(void* const* d_in, const int* in_sizes, int n_in,
                              void* d_out, int out_size, void* d_ws, size_t ws_size,
                              hipStream_t stream) {
    const void* x     = d_in[0];
    const int*  ei    = (const int*)d_in[1];
    const int*  et    = (const int*)d_in[2];
    const void* relw  = d_in[3];
    const void* rootw = d_in[4];
    const void* bias  = d_in[5];
    const void* linw  = d_in[6];
    const void* linb  = d_in[7];

    const size_t WS_NEED = 159547904;
    if (ws_size < WS_NEED) return;

    char* ws = (char*)d_ws;
    ushort_t* Y      = (ushort_t*)(ws);                       // 142,606,336
    ushort_t* Xb     = (ushort_t*)(ws + 142606336);           // 8,388,608
    ushort_t* WT     = (ushort_t*)(ws + 150994944);           // 557,056
    int*      dcnt   = (int*)(ws + 151552000);                // 131,072
    int*      bucket = (int*)(ws + 151683072);                // 7,864,320 (32768*60*4)
    int*      flags  = (int*)(ws + 159547392);                // 256

    prep_k<<<3169, 256, 0, stream>>>(x, relw, rootw, ei, et, Xb, WT, dcnt, flags);
    ge_k<<<EDGEB + GEMMB, 256, 0, stream>>>(Xb, WT, Y, ei, et, dcnt, bucket, flags);
    agg_score_k<<<NNODES, 128, 0, stream>>>(Y, dcnt, bucket, bias, linw, linb, d_out, flags);
}